// Round 4
// baseline (346.287 us; speedup 1.0000x reference)
//
#include <hip/hip_runtime.h>
#include <hip/hip_bf16.h>

// WindowAttentionRPB fused kernel v4, MI355X gfx950.
// 1 block = 1 window, 512 threads = 8 waves = 8 heads.
// All GEMMs in transposed MFMA form (W/P as A-operand, x/V as B-operand):
//   C[c][tok]: tok in lanes, channel in regs.
//   -> Q,K fragments packed IN REGISTERS from QKV accumulators (no LDS trip):
//      S = sum_d Q[q][d]K[kt][d] is invariant to the in-lane d-permutation
//      as long as Q and K use the same packing (verified bijection).
// x read directly from global (L2-hot re-reads), no x staging, no stage barrier.
// LDS 64K total = 8K/wave scratch (vT 4K + P-chunk 4K); attn-out [64][256]
// overlays waves 0-3 scratch after barrier. 2 barriers/block.
// __launch_bounds__(512,2) -> 128-VGPR cap, 2 blocks/CU target.

#define TOK 64
#define CDIM 256

typedef __attribute__((ext_vector_type(8))) short short8;
typedef __attribute__((ext_vector_type(4))) float f32x4;
typedef __attribute__((ext_vector_type(4))) float float4_t;

__device__ __forceinline__ short f2bf(float f) {
  union { float f; unsigned u; } v; v.f = f;
  unsigned r = v.u + 0x7FFFu + ((v.u >> 16) & 1u);
  return (short)(r >> 16);
}

__device__ __forceinline__ short8 pack88(f32x4 lo, f32x4 hi) {
  short8 s;
  s[0] = f2bf(lo[0]); s[1] = f2bf(lo[1]); s[2] = f2bf(lo[2]); s[3] = f2bf(lo[3]);
  s[4] = f2bf(hi[0]); s[5] = f2bf(hi[1]); s[6] = f2bf(hi[2]); s[7] = f2bf(hi[3]);
  return s;
}

// swizzled byte address into a row-major [64][256] bf16 LDS region (512B rows)
__device__ __forceinline__ int rm_addr(int base, int row, int col) {
  return base + row * 512 + ((col * 2) ^ ((row & 7) << 4));
}

__global__ void preconv_kernel(const float* __restrict__ qkv_w,
                               const float* __restrict__ proj_w,
                               const float* __restrict__ rpb_table,
                               const int* __restrict__ rpb_index,
                               const float* __restrict__ mask,
                               short* __restrict__ wqkv,
                               short* __restrict__ wproj,
                               float* __restrict__ rpbT,
                               float* __restrict__ maskT) {
  int idx = blockIdx.x * blockDim.x + threadIdx.x;
  const float scale = 0.17677669529663687f; // 1/sqrt(32), folded into Wq
  const int NW1 = 768 * 256;
  const int NW2 = NW1 + 256 * 256;
  const int NW3 = NW2 + 8 * 64 * 64;
  const int NW4 = NW3 + 64 * 64 * 64;
  if (idx < NW1) {
    float v = qkv_w[idx];
    if (idx < 256 * 256) v *= scale;
    wqkv[idx] = f2bf(v);
  } else if (idx < NW2) {
    int i = idx - NW1;
    wproj[i] = f2bf(proj_w[i]);
  } else if (idx < NW3) {
    int i = idx - NW2;             // [h][qtok][ll*4+ni]
    int h = i >> 12;
    int pos = i & 4095;
    int qtok = pos >> 6;
    int t = pos & 63;
    int llv = t >> 2, ni = t & 3;
    int kt = ni * 16 + llv;
    rpbT[i] = rpb_table[rpb_index[qtok * 64 + kt] * 8 + h];
  } else if (idx < NW4) {
    int i = idx - NW3;             // [win][qtok][ll*4+ni]
    int win = i >> 12;
    int pos = i & 4095;
    int qtok = pos >> 6;
    int t = pos & 63;
    int llv = t >> 2, ni = t & 3;
    int kt = ni * 16 + llv;
    maskT[i] = mask[win * 4096 + qtok * 64 + kt];
  }
}

__global__ void __launch_bounds__(512, 2) fused_attn(
    const float* __restrict__ x, const float* __restrict__ qkv_b,
    const float* __restrict__ proj_b,
    const short* __restrict__ wqkv, const short* __restrict__ wproj,
    const float* __restrict__ rpbT, const float* __restrict__ maskT,
    float* __restrict__ out) {
  extern __shared__ char smem[];
  const int b = blockIdx.x;
  const int tid = threadIdx.x;
  const int w = tid >> 6;      // wave = head
  const int lane = tid & 63;
  const int lg = lane >> 4;    // lane group 0..3
  const int ll = lane & 15;
  const float scale = 0.17677669529663687f;
  const int S0 = w * 8192, S1 = S0 + 4096;  // vT / P-chunk scratch

  // ---- QKV GEMM, transposed: C[c][tok] = W[c][:] . x[tok][:]
  // acc[ni][j]: ni = tok-tile (16 toks), j = 2*sect + hf (c-tile of 16)
  f32x4 acc[4][6] = {};
  const float* xb = x + (size_t)b * TOK * CDIM;
#pragma unroll
  for (int ks = 0; ks < 8; ++ks) {
    const int k0 = ks * 32 + lg * 8;
    short8 xf[4];
#pragma unroll
    for (int ni = 0; ni < 4; ++ni) {
      const float* px = xb + (ni * 16 + ll) * 256 + k0;
      float4_t a0 = *reinterpret_cast<const float4_t*>(px);
      float4_t a1 = *reinterpret_cast<const float4_t*>(px + 4);
      xf[ni] = pack88(a0, a1);
    }
#pragma unroll
    for (int j = 0; j < 6; ++j) {
      const int cbase = (j >> 1) * 256 + w * 32 + (j & 1) * 16;
      short8 wf = *reinterpret_cast<const short8*>(wqkv + (cbase + ll) * 256 + k0);
#pragma unroll
      for (int ni = 0; ni < 4; ++ni)
        acc[ni][j] = __builtin_amdgcn_mfma_f32_16x16x32_bf16(wf, xf[ni], acc[ni][j], 0, 0, 0);
    }
  }

  // ---- biases per c-tile (4 consecutive channels per lane: lg*4 + r)
  f32x4 bj[6];
#pragma unroll
  for (int j = 0; j < 6; ++j) {
    float4_t t = *reinterpret_cast<const float4_t*>(
        qkv_b + (j >> 1) * 256 + w * 32 + (j & 1) * 16 + lg * 4);
    bj[j] = (j < 2) ? t * scale : t;
  }

  // ---- Q/K fragments straight from accumulators (identical packing both
  // sides -> same in-lane d-permutation -> S dot-products correct)
  short8 aq[4], bk[4];
#pragma unroll
  for (int ni = 0; ni < 4; ++ni) {
    aq[ni] = pack88(acc[ni][0] + bj[0], acc[ni][1] + bj[1]);
    bk[ni] = pack88(acc[ni][2] + bj[2], acc[ni][3] + bj[3]);
  }

  // ---- vT [32 d][64 tok] bf16 at S0 (rows 128B, XOR swz (d&7)<<4)
#pragma unroll
  for (int hf = 0; hf < 2; ++hf)
#pragma unroll
    for (int ni = 0; ni < 4; ++ni) {
      f32x4 v4 = acc[ni][4 + hf] + bj[4 + hf];
      int tok = ni * 16 + ll;
#pragma unroll
      for (int r = 0; r < 4; ++r) {
        int d = hf * 16 + lg * 4 + r;
        *reinterpret_cast<short*>(smem + S0 + d * 128 + ((tok * 2) ^ ((d & 7) << 4))) =
            f2bf(v4[r]);
      }
    }

  // ---- S = Q K^T + rpb + mask   (lane: kcol = ni*16+ll; regs: qtok = mi*16+lg*4+r)
  f32x4 sa[4][4];
  {
    f32x4 z{0.0f, 0.0f, 0.0f, 0.0f};
#pragma unroll
    for (int mi = 0; mi < 4; ++mi)
#pragma unroll
      for (int ni = 0; ni < 4; ++ni)
        sa[mi][ni] = __builtin_amdgcn_mfma_f32_16x16x32_bf16(aq[mi], bk[ni], z, 0, 0, 0);
    const float4_t* rpT4 = reinterpret_cast<const float4_t*>(rpbT) + w * 1024;
    const float4_t* mkT4 = reinterpret_cast<const float4_t*>(maskT) + (b & 63) * 1024;
#pragma unroll
    for (int mi = 0; mi < 4; ++mi)
#pragma unroll
      for (int r = 0; r < 4; ++r) {
        int qtok = mi * 16 + lg * 4 + r;
        float4_t f = rpT4[qtok * 16 + ll];
        float4_t g = mkT4[qtok * 16 + ll];
#pragma unroll
        for (int ni = 0; ni < 4; ++ni)
          sa[mi][ni][r] += f[ni] + g[ni];
      }
  }

  // ---- softmax over k-cols (row's 64 cols live in one 16-lane group)
  float rinv[4][4];
#pragma unroll
  for (int mi = 0; mi < 4; ++mi)
#pragma unroll
    for (int r = 0; r < 4; ++r) {
      float m = sa[mi][0][r];
#pragma unroll
      for (int ni = 1; ni < 4; ++ni) m = fmaxf(m, sa[mi][ni][r]);
      for (int d = 1; d < 16; d <<= 1) m = fmaxf(m, __shfl_xor(m, d));
      float sum = 0.f;
#pragma unroll
      for (int ni = 0; ni < 4; ++ni) {
        float e = __expf(sa[mi][ni][r] - m);
        sa[mi][ni][r] = e;
        sum += e;
      }
      for (int d = 1; d < 16; d <<= 1) sum += __shfl_xor(sum, d);
      rinv[mi][r] = 1.0f / sum;
    }

  // ---- PV in two 32-ktok chunks through S1 (wave-local, no barriers)
  f32x4 oa[4][2] = {};
#pragma unroll
  for (int ks = 0; ks < 2; ++ks) {
#pragma unroll
    for (int mi = 0; mi < 4; ++mi)
#pragma unroll
      for (int nio = 0; nio < 2; ++nio) {
        int ni = 2 * ks + nio;
#pragma unroll
        for (int r = 0; r < 4; ++r) {
          int qtok = mi * 16 + lg * 4 + r;
          *reinterpret_cast<short*>(
              smem + S1 + qtok * 64 + (((nio * 16 + ll) * 2) ^ (((qtok >> 1) & 3) << 4))) =
              f2bf(sa[mi][ni][r]);
        }
      }
    short8 ap[4], bv[2];
#pragma unroll
    for (int mi = 0; mi < 4; ++mi) {
      int qt = mi * 16 + ll;
      ap[mi] = *reinterpret_cast<const short8*>(
          smem + S1 + qt * 64 + ((lg * 16) ^ (((qt >> 1) & 3) << 4)));
    }
#pragma unroll
    for (int nj = 0; nj < 2; ++nj) {
      int d = nj * 16 + ll;
      bv[nj] = *reinterpret_cast<const short8*>(
          smem + S0 + d * 128 + (((ks * 32 + lg * 8) * 2) ^ ((d & 7) << 4)));
    }
#pragma unroll
    for (int mi = 0; mi < 4; ++mi)
#pragma unroll
      for (int nj = 0; nj < 2; ++nj)
        oa[mi][nj] = __builtin_amdgcn_mfma_f32_16x16x32_bf16(ap[mi], bv[nj], oa[mi][nj], 0, 0, 0);
  }

  __syncthreads();  // all waves done with own scratch -> [0,32K) reusable

  // ---- attn-out [64][256] bf16 at 0 (normalize rows)
#pragma unroll
  for (int mi = 0; mi < 4; ++mi)
#pragma unroll
    for (int nj = 0; nj < 2; ++nj)
#pragma unroll
      for (int r = 0; r < 4; ++r) {
        int qtok = mi * 16 + lg * 4 + r;
        int ch = w * 32 + nj * 16 + ll;
        float v = oa[mi][nj][r] * rinv[mi][r];
        *reinterpret_cast<short*>(smem + rm_addr(0, qtok, ch)) = f2bf(v);
      }
  __syncthreads();

  // ---- proj, transposed: C[c][tok] = Wp[c][:] . attnout[tok][:]
  f32x4 pa[2][4] = {};
#pragma unroll
  for (int ks = 0; ks < 8; ++ks) {
    const int k0 = ks * 32 + lg * 8;
    short8 af[4];
#pragma unroll
    for (int ni = 0; ni < 4; ++ni)
      af[ni] = *reinterpret_cast<const short8*>(smem + rm_addr(0, ni * 16 + ll, k0));
#pragma unroll
    for (int j = 0; j < 2; ++j) {
      short8 wf = *reinterpret_cast<const short8*>(wproj + (w * 32 + j * 16 + ll) * 256 + k0);
#pragma unroll
      for (int ni = 0; ni < 4; ++ni)
        pa[j][ni] = __builtin_amdgcn_mfma_f32_16x16x32_bf16(wf, af[ni], pa[j][ni], 0, 0, 0);
    }
  }
  // ---- store: lane holds 4 consecutive channels -> dwordx4
  float* outp = out + (size_t)b * TOK * CDIM;
#pragma unroll
  for (int j = 0; j < 2; ++j) {
    float4_t pb = *reinterpret_cast<const float4_t*>(proj_b + w * 32 + j * 16 + lg * 4);
#pragma unroll
    for (int ni = 0; ni < 4; ++ni) {
      f32x4 v = pa[j][ni] + pb;
      *reinterpret_cast<float4_t*>(outp + (ni * 16 + ll) * 256 + w * 32 + j * 16 + lg * 4) = v;
    }
  }
}

extern "C" void kernel_launch(void* const* d_in, const int* in_sizes, int n_in,
                              void* d_out, int out_size, void* d_ws, size_t ws_size,
                              hipStream_t stream) {
  const float* x        = (const float*)d_in[0];
  const float* mask     = (const float*)d_in[1];
  const float* qkv_w    = (const float*)d_in[2];
  const float* qkv_b    = (const float*)d_in[3];
  const float* proj_w   = (const float*)d_in[4];
  const float* proj_b   = (const float*)d_in[5];
  const float* rpb_tab  = (const float*)d_in[6];
  const int*   rpb_idx  = (const int*)d_in[7];
  float* out = (float*)d_out;

  short* wqkv  = (short*)d_ws;                  // 196608 shorts
  short* wproj = wqkv + 768 * 256;              // 65536 shorts
  float* rpbT  = (float*)(wproj + 256 * 256);   // 32768 floats
  float* maskT = rpbT + 8 * 64 * 64;            // 262144 floats

  int total = 768 * 256 + 256 * 256 + 8 * 64 * 64 + 64 * 64 * 64;
  preconv_kernel<<<(total + 255) / 256, 256, 0, stream>>>(
      qkv_w, proj_w, rpb_tab, rpb_idx, mask, wqkv, wproj, rpbT, maskT);

  hipFuncSetAttribute((const void*)fused_attn,
                      hipFuncAttributeMaxDynamicSharedMemorySize, 65536);
  int B = in_sizes[0] / (TOK * CDIM);  // 2048
  fused_attn<<<B, 512, 65536, stream>>>(x, qkv_b, proj_b, wqkv, wproj,
                                        rpbT, maskT, out);
}

// Round 5
// 248.579 us; speedup vs baseline: 1.3931x; 1.3931x over previous
//
#include <hip/hip_runtime.h>
#include <hip/hip_bf16.h>

// WindowAttentionRPB fused kernel v5, MI355X gfx950.
// 1 block = 1 window, 512 threads = 8 waves = 8 heads.
// Q/K never touch LDS (register fragment trick: identical A/B lane maps +
// shared in-lane d-permutation cancels in S = Q K^T).
// V computed in normal orientation from the same x fragments -> vT written
// as packed b64. PV computed as O^T = V^T P^T -> attn-out written as b64.
// All f32->bf16 via __float22bfloat162_rn (packed cvt).
// LDS 96K: x [64][256]bf16 swz at 0; per-wave 8K scratch (vT 4K + P-chunk 4K)
// at 32K+w*8K; attn-out [64][256] overlays waves0-3 scratch after barrier2.
// 3 barriers. __launch_bounds__(512): 256-reg cap (8 waves/CU), no spills.

#define TOK 64
#define CDIM 256
#define SCRB 32768
#define AT   32768

typedef __attribute__((ext_vector_type(8))) short short8;
typedef __attribute__((ext_vector_type(4))) float f32x4;
typedef __attribute__((ext_vector_type(4))) float float4_t;

__device__ __forceinline__ short f2bf(float f) {
  union { float f; unsigned u; } v; v.f = f;
  unsigned r = v.u + 0x7FFFu + ((v.u >> 16) & 1u);
  return (short)(r >> 16);
}

__device__ __forceinline__ unsigned cvt2(float a, float b) {
  union { __hip_bfloat162 h; unsigned u; } v;
  v.h = __float22bfloat162_rn(make_float2(a, b));
  return v.u;
}

__device__ __forceinline__ short8 pack88(f32x4 lo, f32x4 hi) {
  union { short8 s; unsigned u[4]; } r;
  r.u[0] = cvt2(lo[0], lo[1]);
  r.u[1] = cvt2(lo[2], lo[3]);
  r.u[2] = cvt2(hi[0], hi[1]);
  r.u[3] = cvt2(hi[2], hi[3]);
  return r.s;
}

// swizzled byte address into a row-major [64][256] bf16 LDS region (512B rows)
__device__ __forceinline__ int rm_addr(int base, int row, int col) {
  return base + row * 512 + ((col * 2) ^ ((row & 7) << 4));
}

__global__ void preconv_kernel(const float* __restrict__ qkv_w,
                               const float* __restrict__ proj_w,
                               const float* __restrict__ rpb_table,
                               const int* __restrict__ rpb_index,
                               const float* __restrict__ mask,
                               short* __restrict__ wqkv,
                               short* __restrict__ wproj,
                               float* __restrict__ rpbT,
                               float* __restrict__ maskT) {
  int idx = blockIdx.x * blockDim.x + threadIdx.x;
  const float scale = 0.17677669529663687f; // 1/sqrt(32), folded into Wq
  const int NW1 = 768 * 256;
  const int NW2 = NW1 + 256 * 256;
  const int NW3 = NW2 + 8 * 64 * 64;
  const int NW4 = NW3 + 64 * 64 * 64;
  if (idx < NW1) {
    float v = qkv_w[idx];
    if (idx < 256 * 256) v *= scale;
    wqkv[idx] = f2bf(v);
  } else if (idx < NW2) {
    int i = idx - NW1;
    wproj[i] = f2bf(proj_w[i]);
  } else if (idx < NW3) {
    int i = idx - NW2;             // [h][qtok][ll*4+ni]
    int h = i >> 12;
    int pos = i & 4095;
    int qtok = pos >> 6;
    int t = pos & 63;
    int llv = t >> 2, ni = t & 3;
    int kt = ni * 16 + llv;
    rpbT[i] = rpb_table[rpb_index[qtok * 64 + kt] * 8 + h];
  } else if (idx < NW4) {
    int i = idx - NW3;             // [win][qtok][ll*4+ni]
    int win = i >> 12;
    int pos = i & 4095;
    int qtok = pos >> 6;
    int t = pos & 63;
    int llv = t >> 2, ni = t & 3;
    int kt = ni * 16 + llv;
    maskT[i] = mask[win * 4096 + qtok * 64 + kt];
  }
}

__global__ void __launch_bounds__(512) fused_attn(
    const float* __restrict__ x, const float* __restrict__ qkv_b,
    const float* __restrict__ proj_b,
    const short* __restrict__ wqkv, const short* __restrict__ wproj,
    const float* __restrict__ rpbT, const float* __restrict__ maskT,
    float* __restrict__ out) {
  extern __shared__ char smem[];
  const int b = blockIdx.x;
  const int tid = threadIdx.x;
  const int w = tid >> 6;      // wave = head
  const int lane = tid & 63;
  const int lg = lane >> 4;    // lane group 0..3
  const int ll = lane & 15;
  const float scale = 0.17677669529663687f;
  const int S0 = SCRB + w * 8192;      // vT   [32 d][64 tok], 128B rows
  const int S1 = S0 + 4096;            // P-chunk [64 qtok][32 kt], 64B rows

  // ---- stage x -> LDS bf16 swizzled at 0 ([64][256])
  {
    const int row = tid >> 3;
    const int c0 = (tid & 7) * 32;
    const float4_t* src = reinterpret_cast<const float4_t*>(
        x + (size_t)b * TOK * CDIM + row * CDIM + c0);
#pragma unroll
    for (int j = 0; j < 4; ++j) {
      float4_t f0 = src[2 * j];
      float4_t f1 = src[2 * j + 1];
      *reinterpret_cast<short8*>(smem + rm_addr(0, row, c0 + 8 * j)) =
          pack88(f0, f1);
    }
  }
  __syncthreads();

  // ---- loop A: Q,K in transposed form  C[c][tok] = W[c][:] . x[tok][:]
  // aqk[ni][j]: ni = tok-tile (col), j = 2*(is_k) + c-halftile (rows)
  f32x4 aqk[4][4] = {};
#pragma unroll
  for (int ks = 0; ks < 8; ++ks) {
    const int k0 = ks * 32 + lg * 8;
    short8 xf[4];
#pragma unroll
    for (int ni = 0; ni < 4; ++ni)
      xf[ni] = *reinterpret_cast<const short8*>(smem + rm_addr(0, ni * 16 + ll, k0));
#pragma unroll
    for (int j = 0; j < 4; ++j) {
      const int cbase = (j >> 1) * 256 + w * 32 + (j & 1) * 16;
      short8 wf = *reinterpret_cast<const short8*>(wqkv + (cbase + ll) * 256 + k0);
#pragma unroll
      for (int ni = 0; ni < 4; ++ni)
        aqk[ni][j] = __builtin_amdgcn_mfma_f32_16x16x32_bf16(wf, xf[ni], aqk[ni][j], 0, 0, 0);
    }
  }
  // biases (4 consecutive channels per lane: lg*4+r rows of transposed C)
  f32x4 bj[4];
#pragma unroll
  for (int j = 0; j < 4; ++j) {
    float4_t t = *reinterpret_cast<const float4_t*>(
        qkv_b + (j >> 1) * 256 + w * 32 + (j & 1) * 16 + lg * 4);
    bj[j] = (j < 2) ? t * scale : t;
  }
  // Q/K fragments straight from accumulators (shared d-permutation cancels)
  short8 aq[4], bk[4];
#pragma unroll
  for (int ni = 0; ni < 4; ++ni) {
    aq[ni] = pack88(aqk[ni][0] + bj[0], aqk[ni][1] + bj[1]);
    bk[ni] = pack88(aqk[ni][2] + bj[2], aqk[ni][3] + bj[3]);
  }

  // ---- loop B: V in normal form  C[tok][d] = x[tok][:] . Wv[d][:]
  f32x4 av[4][2] = {};
#pragma unroll
  for (int ks = 0; ks < 8; ++ks) {
    const int k0 = ks * 32 + lg * 8;
    short8 xf[4];
#pragma unroll
    for (int mi = 0; mi < 4; ++mi)
      xf[mi] = *reinterpret_cast<const short8*>(smem + rm_addr(0, mi * 16 + ll, k0));
#pragma unroll
    for (int hf = 0; hf < 2; ++hf) {
      short8 wfv = *reinterpret_cast<const short8*>(
          wqkv + (512 + w * 32 + hf * 16 + ll) * 256 + k0);
#pragma unroll
      for (int mi = 0; mi < 4; ++mi)
        av[mi][hf] = __builtin_amdgcn_mfma_f32_16x16x32_bf16(xf[mi], wfv, av[mi][hf], 0, 0, 0);
    }
  }
  // vT [d][tok] writes: lane has fixed d = hf*16+ll, 4 consecutive toks -> b64
#pragma unroll
  for (int hf = 0; hf < 2; ++hf) {
    float bb = qkv_b[512 + w * 32 + hf * 16 + ll];
    int d = hf * 16 + ll;
#pragma unroll
    for (int mi = 0; mi < 4; ++mi) {
      f32x4 v = av[mi][hf];
      int tok0 = 16 * mi + lg * 4;
      union { unsigned long long q; unsigned u[2]; } pk;
      pk.u[0] = cvt2(v[0] + bb, v[1] + bb);
      pk.u[1] = cvt2(v[2] + bb, v[3] + bb);
      *reinterpret_cast<unsigned long long*>(
          smem + S0 + d * 128 + ((tok0 * 2) ^ ((d & 7) << 4))) = pk.q;
    }
  }

  // ---- S = Q K^T + rpb + mask  (lane: kcol = ni*16+ll; regs: qtok = 16mi+lg*4+r)
  f32x4 sa[4][4];
  {
    f32x4 z{0.0f, 0.0f, 0.0f, 0.0f};
#pragma unroll
    for (int mi = 0; mi < 4; ++mi)
#pragma unroll
      for (int ni = 0; ni < 4; ++ni)
        sa[mi][ni] = __builtin_amdgcn_mfma_f32_16x16x32_bf16(aq[mi], bk[ni], z, 0, 0, 0);
    const float4_t* rpT4 = reinterpret_cast<const float4_t*>(rpbT) + w * 1024;
    const float4_t* mkT4 = reinterpret_cast<const float4_t*>(maskT) + (b & 63) * 1024;
#pragma unroll
    for (int mi = 0; mi < 4; ++mi)
#pragma unroll
      for (int r = 0; r < 4; ++r) {
        int qtok = mi * 16 + lg * 4 + r;
        float4_t f = rpT4[qtok * 16 + ll];
        float4_t g = mkT4[qtok * 16 + ll];
#pragma unroll
        for (int ni = 0; ni < 4; ++ni)
          sa[mi][ni][r] += f[ni] + g[ni];
      }
  }

  // ---- softmax over k-cols (each row's 64 cols live in one 16-lane group)
  float rinv[4][4];
#pragma unroll
  for (int mi = 0; mi < 4; ++mi)
#pragma unroll
    for (int r = 0; r < 4; ++r) {
      float m = sa[mi][0][r];
#pragma unroll
      for (int ni = 1; ni < 4; ++ni) m = fmaxf(m, sa[mi][ni][r]);
      for (int d = 1; d < 16; d <<= 1) m = fmaxf(m, __shfl_xor(m, d));
      float sum = 0.f;
#pragma unroll
      for (int ni = 0; ni < 4; ++ni) {
        float e = __expf(sa[mi][ni][r] - m);
        sa[mi][ni][r] = e;
        sum += e;
      }
      for (int d = 1; d < 16; d <<= 1) sum += __shfl_xor(sum, d);
      rinv[mi][r] = 1.0f / sum;
    }

  // ---- PV as O^T = V^T P^T, in two 32-kt chunks through S1 (wave-local)
  // oa[hf][ni]: rows d = 16hf+lg*4+r, col qtok = ll+16ni
  f32x4 oa[2][4] = {};
#pragma unroll
  for (int ks = 0; ks < 2; ++ks) {
    // write normalized P chunk [64 qtok][32 kt']
#pragma unroll
    for (int mi = 0; mi < 4; ++mi)
#pragma unroll
      for (int nio = 0; nio < 2; ++nio) {
        int ni = 2 * ks + nio;
        unsigned u01 = cvt2(sa[mi][ni][0] * rinv[mi][0], sa[mi][ni][1] * rinv[mi][1]);
        unsigned u23 = cvt2(sa[mi][ni][2] * rinv[mi][2], sa[mi][ni][3] * rinv[mi][3]);
        int col2 = (nio * 16 + ll) * 2;
        int qt0 = 16 * mi + lg * 4;
        *reinterpret_cast<short*>(smem + S1 + (qt0 + 0) * 64 + (col2 ^ (((qt0 + 0) & 3) << 4))) = (short)(u01);
        *reinterpret_cast<short*>(smem + S1 + (qt0 + 1) * 64 + (col2 ^ (((qt0 + 1) & 3) << 4))) = (short)(u01 >> 16);
        *reinterpret_cast<short*>(smem + S1 + (qt0 + 2) * 64 + (col2 ^ (((qt0 + 2) & 3) << 4))) = (short)(u23);
        *reinterpret_cast<short*>(smem + S1 + (qt0 + 3) * 64 + (col2 ^ (((qt0 + 3) & 3) << 4))) = (short)(u23 >> 16);
      }
    // B-frags: col qtok, k = kt'
    short8 pf[4], vf[2];
#pragma unroll
    for (int ni = 0; ni < 4; ++ni) {
      int qt = ll + 16 * ni;
      pf[ni] = *reinterpret_cast<const short8*>(
          smem + S1 + qt * 64 + ((lg * 16) ^ ((qt & 3) << 4)));
    }
#pragma unroll
    for (int hf = 0; hf < 2; ++hf) {
      int d = ll + 16 * hf;
      vf[hf] = *reinterpret_cast<const short8*>(
          smem + S0 + d * 128 + (((ks * 32 + lg * 8) * 2) ^ ((d & 7) << 4)));
    }
#pragma unroll
    for (int hf = 0; hf < 2; ++hf)
#pragma unroll
      for (int ni = 0; ni < 4; ++ni)
        oa[hf][ni] = __builtin_amdgcn_mfma_f32_16x16x32_bf16(vf[hf], pf[ni], oa[hf][ni], 0, 0, 0);
  }

  __syncthreads();  // all waves done with x + own scratch -> AT writable

  // ---- attn-out [64 qtok][256 ch] bf16 at AT; lane has 4 consecutive ch -> b64
#pragma unroll
  for (int hf = 0; hf < 2; ++hf)
#pragma unroll
    for (int ni = 0; ni < 4; ++ni) {
      int qt = ll + 16 * ni;
      int ch0 = w * 32 + hf * 16 + lg * 4;
      union { unsigned long long q; unsigned u[2]; } pk;
      pk.u[0] = cvt2(oa[hf][ni][0], oa[hf][ni][1]);
      pk.u[1] = cvt2(oa[hf][ni][2], oa[hf][ni][3]);
      *reinterpret_cast<unsigned long long*>(
          smem + AT + qt * 512 + ((ch0 * 2) ^ ((qt & 7) << 4))) = pk.q;
    }
  __syncthreads();

  // ---- proj, transposed: C[oc][tok] = Wp[oc][:] . attnout[tok][:]
  f32x4 pa[2][4] = {};
#pragma unroll
  for (int ks = 0; ks < 8; ++ks) {
    const int k0 = ks * 32 + lg * 8;
    short8 af[4];
#pragma unroll
    for (int ni = 0; ni < 4; ++ni)
      af[ni] = *reinterpret_cast<const short8*>(smem + rm_addr(AT, ni * 16 + ll, k0));
#pragma unroll
    for (int j = 0; j < 2; ++j) {
      short8 wf = *reinterpret_cast<const short8*>(wproj + (w * 32 + j * 16 + ll) * 256 + k0);
#pragma unroll
      for (int ni = 0; ni < 4; ++ni)
        pa[j][ni] = __builtin_amdgcn_mfma_f32_16x16x32_bf16(wf, af[ni], pa[j][ni], 0, 0, 0);
    }
  }
  // ---- store: lane holds 4 consecutive channels -> dwordx4
  float* outp = out + (size_t)b * TOK * CDIM;
#pragma unroll
  for (int j = 0; j < 2; ++j) {
    float4_t pb = *reinterpret_cast<const float4_t*>(proj_b + w * 32 + j * 16 + lg * 4);
#pragma unroll
    for (int ni = 0; ni < 4; ++ni) {
      f32x4 v = pa[j][ni] + pb;
      *reinterpret_cast<float4_t*>(outp + (ni * 16 + ll) * 256 + w * 32 + j * 16 + lg * 4) = v;
    }
  }
}

extern "C" void kernel_launch(void* const* d_in, const int* in_sizes, int n_in,
                              void* d_out, int out_size, void* d_ws, size_t ws_size,
                              hipStream_t stream) {
  const float* x        = (const float*)d_in[0];
  const float* mask     = (const float*)d_in[1];
  const float* qkv_w    = (const float*)d_in[2];
  const float* qkv_b    = (const float*)d_in[3];
  const float* proj_w   = (const float*)d_in[4];
  const float* proj_b   = (const float*)d_in[5];
  const float* rpb_tab  = (const float*)d_in[6];
  const int*   rpb_idx  = (const int*)d_in[7];
  float* out = (float*)d_out;

  short* wqkv  = (short*)d_ws;                  // 196608 shorts
  short* wproj = wqkv + 768 * 256;              // 65536 shorts
  float* rpbT  = (float*)(wproj + 256 * 256);   // 32768 floats
  float* maskT = rpbT + 8 * 64 * 64;            // 262144 floats

  int total = 768 * 256 + 256 * 256 + 8 * 64 * 64 + 64 * 64 * 64;
  preconv_kernel<<<(total + 255) / 256, 256, 0, stream>>>(
      qkv_w, proj_w, rpb_tab, rpb_idx, mask, wqkv, wproj, rpbT, maskT);

  hipFuncSetAttribute((const void*)fused_attn,
                      hipFuncAttributeMaxDynamicSharedMemorySize, 98304);
  int B = in_sizes[0] / (TOK * CDIM);  // 2048
  fused_attn<<<B, 512, 98304, stream>>>(x, qkv_b, proj_b, wqkv, wproj,
                                        rpbT, maskT, out);
}